// Round 4
// baseline (612.055 us; speedup 1.0000x reference)
//
#include <hip/hip_runtime.h>

// SparK densify: channels-first LayerNorm + mask-token fill + 1x1 conv (128->128).
// B=32, C=128, H=W=128, D=128. fp32 in, fp32 out (established round 2/3: d_out is fp32;
// mask arrives as int32 bools per harness "integer -> const int*" rule).
// Runtime probes (uniform, capture-safe) guard both dtype assumptions:
//   gamma==ones -> first u32 is 0x3F800000 (fp32) or 0x3F803F80 (bf16 pair)
//   mask int32 iff first 16 u32 words of act are all <=1 (byte-bools fail w.h.p.)

#define CC   128
#define DD   128
#define HWW  16384
#define PP   128
#define NTHREADS 512

__device__ __forceinline__ float b2f(unsigned short u) {
    return __uint_as_float(((unsigned int)u) << 16);
}
__device__ __forceinline__ float ldf(const void* p, int i, bool bf) {
    return bf ? b2f(((const unsigned short*)p)[i]) : ((const float*)p)[i];
}

__global__ void prep_transpose_w(const void* __restrict__ w, float* __restrict__ wT,
                                 const void* __restrict__ gamma) {
    const bool bf = (((const unsigned int*)gamma)[0] == 0x3F803F80u);
    int idx = blockIdx.x * blockDim.x + threadIdx.x;   // 0..16383
    int d = idx >> 7, c = idx & 127;
    wT[c * DD + d] = ldf(w, idx, bf);                  // w is (D,C)
}

__global__ __launch_bounds__(NTHREADS, 4)
void spark_densify_kernel(const void* __restrict__ x,     // (B,C,H,W) fp32 (probe-guarded)
                          const void* __restrict__ act,   // (B,1,H,W) bool (i32 or u8)
                          const void* __restrict__ gamma, // (C)
                          const void* __restrict__ beta,  // (C)
                          const void* __restrict__ mtok,  // (C)
                          const float* __restrict__ wT,   // (C,D) fp32, from prep
                          const void* __restrict__ bias,  // (D)
                          float* __restrict__ out)        // (B,D,H,W) fp32
{
    __shared__ __align__(16) float tile[CC][PP];   // 64 KiB
    __shared__ __align__(16) float ps_s[8][PP];    // 4 KiB
    __shared__ __align__(16) float ps_q[8][PP];    // 4 KiB
    __shared__ __align__(16) float st_mu[PP];
    __shared__ __align__(16) float st_rs[PP];

    const int t    = threadIdx.x;
    const int bk   = blockIdx.x;          // 0..4095
    const int b    = bk >> 7;
    const int pos0 = (bk & 127) * PP;

    // ---- runtime dtype probes (uniform across all threads/blocks) ----
    const bool bf = (((const unsigned int*)gamma)[0] == 0x3F803F80u);
    bool mint = true;
    #pragma unroll
    for (int i = 0; i < 16; ++i) mint = mint && (((const unsigned int*)act)[i] <= 1u);

    // ---------- phase 1: stage C x P tile + register partial stats ----------
    const int pq = t & 31;                // position-quad 0..31
    const int cg = t >> 5;                // channel-group 0..15 (8 ch each)
    const long xbase = (long)b * CC * HWW + pos0 + pq * 4;

    float s0=0.f,s1=0.f,s2=0.f,s3=0.f;
    float q0=0.f,q1=0.f,q2=0.f,q3=0.f;
    if (!bf) {
        const float* xf = (const float*)x;
        #pragma unroll
        for (int i = 0; i < 8; ++i) {
            const int c = cg * 8 + i;
            const float4 v = *(const float4*)(xf + xbase + (long)c * HWW);
            *(float4*)&tile[c][pq * 4] = v;
            s0 += v.x; q0 = fmaf(v.x, v.x, q0);
            s1 += v.y; q1 = fmaf(v.y, v.y, q1);
            s2 += v.z; q2 = fmaf(v.z, v.z, q2);
            s3 += v.w; q3 = fmaf(v.w, v.w, q3);
        }
    } else {
        const unsigned short* xh = (const unsigned short*)x;
        #pragma unroll
        for (int i = 0; i < 8; ++i) {
            const int c = cg * 8 + i;
            const ushort4 u = *(const ushort4*)(xh + xbase + (long)c * HWW);
            const float4 v = make_float4(b2f(u.x), b2f(u.y), b2f(u.z), b2f(u.w));
            *(float4*)&tile[c][pq * 4] = v;
            s0 += v.x; q0 = fmaf(v.x, v.x, q0);
            s1 += v.y; q1 = fmaf(v.y, v.y, q1);
            s2 += v.z; q2 = fmaf(v.z, v.z, q2);
            s3 += v.w; q3 = fmaf(v.w, v.w, q3);
        }
    }
    // lanes l and l+32 hold same positions, adjacent channel-groups
    s0 += __shfl_xor(s0, 32); q0 += __shfl_xor(q0, 32);
    s1 += __shfl_xor(s1, 32); q1 += __shfl_xor(q1, 32);
    s2 += __shfl_xor(s2, 32); q2 += __shfl_xor(q2, 32);
    s3 += __shfl_xor(s3, 32); q3 += __shfl_xor(q3, 32);

    const int wv   = t >> 6;
    const int lane = t & 63;
    if (lane < 32) {
        *(float4*)&ps_s[wv][lane * 4] = make_float4(s0, s1, s2, s3);
        *(float4*)&ps_q[wv][lane * 4] = make_float4(q0, q1, q2, q3);
    }
    __syncthreads();

    // ---------- phase 2: finalize per-position stats ----------
    if (t < PP) {
        float ss = 0.f, qq = 0.f;
        #pragma unroll
        for (int wvi = 0; wvi < 8; ++wvi) { ss += ps_s[wvi][t]; qq += ps_q[wvi][t]; }
        const float mu  = ss * (1.0f / 128.0f);
        const float var = qq * (1.0f / 128.0f) - mu * mu;
        st_mu[t] = mu;
        st_rs[t] = rsqrtf(var + 1e-6f);
    }
    __syncthreads();

    // ---------- phase 3: normalize + mask fill ----------
    {
        const long aoff = (long)b * HWW + pos0 + pq * 4;
        uchar4 a4;
        if (mint) {
            const int4 m = *(const int4*)((const int*)act + aoff);
            a4.x = (unsigned char)(m.x != 0); a4.y = (unsigned char)(m.y != 0);
            a4.z = (unsigned char)(m.z != 0); a4.w = (unsigned char)(m.w != 0);
        } else {
            a4 = *(const uchar4*)((const unsigned char*)act + aoff);
        }
        const float4 muv = *(const float4*)&st_mu[pq * 4];
        const float4 rsv = *(const float4*)&st_rs[pq * 4];
        #pragma unroll
        for (int i = 0; i < 8; ++i) {
            const int c = cg * 8 + i;
            const float g  = ldf(gamma, c, bf);
            const float be = ldf(beta,  c, bf);
            const float mt = ldf(mtok,  c, bf);
            float4 v = *(float4*)&tile[c][pq * 4];
            v.x = a4.x ? fmaf((v.x - muv.x) * rsv.x, g, be) : mt;
            v.y = a4.y ? fmaf((v.y - muv.y) * rsv.y, g, be) : mt;
            v.z = a4.z ? fmaf((v.z - muv.z) * rsv.z, g, be) : mt;
            v.w = a4.w ? fmaf((v.w - muv.w) * rsv.w, g, be) : mt;
            *(float4*)&tile[c][pq * 4] = v;
        }
    }
    __syncthreads();

    // ---------- phase 4: 1x1 conv matvec ----------
    const int d0 = __builtin_amdgcn_readfirstlane(wv) * 16;  // wave-uniform -> s_loads
    const int p2 = lane * 2;

    float acc[16][2];
    #pragma unroll
    for (int j = 0; j < 16; ++j) { acc[j][0] = 0.f; acc[j][1] = 0.f; }

    #pragma unroll 2
    for (int c = 0; c < CC; ++c) {
        const float2 xv = *(const float2*)&tile[c][p2];
        const float* wr = wT + c * DD + d0;
        #pragma unroll
        for (int j = 0; j < 16; ++j) {
            const float wj = wr[j];
            acc[j][0] = fmaf(wj, xv.x, acc[j][0]);
            acc[j][1] = fmaf(wj, xv.y, acc[j][1]);
        }
    }

    // epilogue: bias + coalesced float2 stores (fp32 output)
    const long obase = (long)b * DD * HWW + pos0 + p2;
    #pragma unroll
    for (int j = 0; j < 16; ++j) {
        const float bb = ldf(bias, d0 + j, bf);
        float2 o;
        o.x = acc[j][0] + bb;
        o.y = acc[j][1] + bb;
        *(float2*)(out + obase + (long)(d0 + j) * HWW) = o;
    }
}

extern "C" void kernel_launch(void* const* d_in, const int* in_sizes, int n_in,
                              void* d_out, int out_size, void* d_ws, size_t ws_size,
                              hipStream_t stream) {
    const void* x     = d_in[0];
    const void* act   = d_in[1];
    const void* gamma = d_in[2];
    const void* beta  = d_in[3];
    const void* mtok  = d_in[4];
    const void* convw = d_in[5];
    const void* bias  = d_in[6];
    float* out = (float*)d_out;          // fp32 (confirmed by round-2/3 error forensics)
    float* wT  = (float*)d_ws;           // 64 KiB scratch

    prep_transpose_w<<<64, 256, 0, stream>>>(convw, wT, gamma);

    const int nblocks = (32 * HWW) / PP;   // 4096
    spark_densify_kernel<<<nblocks, NTHREADS, 0, stream>>>(
        x, act, gamma, beta, mtok, wT, bias, out);
}

// Round 5
// 452.191 us; speedup vs baseline: 1.3535x; 1.3535x over previous
//
#include <hip/hip_runtime.h>

// SparK densify: channels-first LayerNorm + mask-token fill + 1x1 conv (128->128).
// B=32, C=128, H=W=128, D=128. fp32 in/out (confirmed R2-R4); mask = int32 bools.
// R5: conv moved to MFMA (bf16): D[p,d] = sum_c Xn^T[p,c] * W^T[c,d] via
// mfma_f32_16x16x32_bf16. Raw x lives in registers (no fp32 LDS tile);
// LDS holds only the A-fragment staging (32KB, slot^p_tile swizzle, conflict-free)
// + LN stat partials. Weights prepacked to B-frag order bf16 in d_ws.

#define CC   128
#define DD   128
#define HWW  16384
#define PP   128
#define NTHREADS 512

typedef __attribute__((ext_vector_type(8))) short short8;
typedef __attribute__((ext_vector_type(4))) float f32x4;

__device__ __forceinline__ float b2f(unsigned short u) {
    return __uint_as_float(((unsigned int)u) << 16);
}
__device__ __forceinline__ unsigned short f2b(float f) {   // RNE fp32->bf16
    unsigned int u = __float_as_uint(f);
    return (unsigned short)((u + 0x7FFFu + ((u >> 16) & 1u)) >> 16);
}
__device__ __forceinline__ unsigned int pk2(float lo, float hi) {
    return (unsigned int)f2b(lo) | ((unsigned int)f2b(hi) << 16);
}
__device__ __forceinline__ float ldf(const void* p, int i, bool bf) {
    return bf ? b2f(((const unsigned short*)p)[i]) : ((const float*)p)[i];
}

// Pack conv_w (D,C) into B-fragment order bf16:
// wpack[((wv*4+kk)*64 + lane)*8 + j] = w[wv*16 + (lane&15)][kk*32 + (lane>>4)*8 + j]
__global__ void prep_pack_w(const void* __restrict__ w, unsigned short* __restrict__ wpack,
                            const void* __restrict__ gamma) {
    const bool bf = (((const unsigned int*)gamma)[0] == 0x3F803F80u);
    int e = blockIdx.x * blockDim.x + threadIdx.x;   // 0..16383
    int j = e & 7, lane = (e >> 3) & 63, kk = (e >> 9) & 3, wv = e >> 11;
    int d = wv * 16 + (lane & 15);
    int c = kk * 32 + ((lane >> 4) & 3) * 8 + j;
    wpack[e] = f2b(ldf(w, d * CC + c, bf));
}

__global__ __launch_bounds__(NTHREADS, 4)
void spark_densify_mfma(const void* __restrict__ x,     // (B,C,H,W) fp32 (probe-guarded)
                        const void* __restrict__ act,   // (B,1,H,W) bool (i32 or u8)
                        const void* __restrict__ gam,   // (C)
                        const void* __restrict__ bet,   // (C)
                        const void* __restrict__ mtok,  // (C)
                        const unsigned short* __restrict__ wpack, // B-frags bf16
                        const void* __restrict__ bias,  // (D)
                        float* __restrict__ out)        // (B,D,H,W) fp32
{
    __shared__ __align__(16) uint4 afrag[8 * 4 * 64];  // 32KB A-frag staging
    __shared__ float ps_s[8][PP];                      // 4KB
    __shared__ float ps_q[8][PP];                      // 4KB
    __shared__ float st_mu[PP];
    __shared__ float st_rs[PP];

    const int t    = threadIdx.x;
    const int bk   = blockIdx.x;          // 0..4095
    const int b    = bk >> 7;
    const int pos0 = (bk & 127) * PP;

    // ---- runtime dtype probes (uniform) ----
    const bool bf = (((const unsigned int*)gam)[0] == 0x3F803F80u);
    bool mint = true;
    #pragma unroll
    for (int i = 0; i < 16; ++i) mint = mint && (((const unsigned int*)act)[i] <= 1u);

    // ---------- phase 1: load x into regs + partial stats ----------
    const int pq = t & 31;                // position-quad 0..31 (p = pq*4..pq*4+3)
    const int cg = t >> 5;                // channel-group 0..15 (c = cg*8..cg*8+7)
    const long xbase = (long)b * CC * HWW + pos0 + pq * 4;

    float4 v[8];
    float s0=0.f,s1=0.f,s2=0.f,s3=0.f;
    float q0=0.f,q1=0.f,q2=0.f,q3=0.f;
    if (!bf) {
        const float* xf = (const float*)x;
        #pragma unroll
        for (int i = 0; i < 8; ++i) {
            v[i] = *(const float4*)(xf + xbase + (long)(cg * 8 + i) * HWW);
            s0 += v[i].x; q0 = fmaf(v[i].x, v[i].x, q0);
            s1 += v[i].y; q1 = fmaf(v[i].y, v[i].y, q1);
            s2 += v[i].z; q2 = fmaf(v[i].z, v[i].z, q2);
            s3 += v[i].w; q3 = fmaf(v[i].w, v[i].w, q3);
        }
    } else {
        const unsigned short* xh = (const unsigned short*)x;
        #pragma unroll
        for (int i = 0; i < 8; ++i) {
            const ushort4 u = *(const ushort4*)(xh + xbase + (long)(cg * 8 + i) * HWW);
            v[i] = make_float4(b2f(u.x), b2f(u.y), b2f(u.z), b2f(u.w));
            s0 += v[i].x; q0 = fmaf(v[i].x, v[i].x, q0);
            s1 += v[i].y; q1 = fmaf(v[i].y, v[i].y, q1);
            s2 += v[i].z; q2 = fmaf(v[i].z, v[i].z, q2);
            s3 += v[i].w; q3 = fmaf(v[i].w, v[i].w, q3);
        }
    }
    s0 += __shfl_xor(s0, 32); q0 += __shfl_xor(q0, 32);
    s1 += __shfl_xor(s1, 32); q1 += __shfl_xor(q1, 32);
    s2 += __shfl_xor(s2, 32); q2 += __shfl_xor(q2, 32);
    s3 += __shfl_xor(s3, 32); q3 += __shfl_xor(q3, 32);

    const int wv_  = t >> 6;
    const int lane = t & 63;
    if (lane < 32) {
        *(float4*)&ps_s[wv_][lane * 4] = make_float4(s0, s1, s2, s3);
        *(float4*)&ps_q[wv_][lane * 4] = make_float4(q0, q1, q2, q3);
    }
    __syncthreads();

    // ---------- phase 2: finalize per-position stats ----------
    if (t < PP) {
        float ss = 0.f, qq = 0.f;
        #pragma unroll
        for (int w8 = 0; w8 < 8; ++w8) { ss += ps_s[w8][t]; qq += ps_q[w8][t]; }
        const float mu  = ss * (1.0f / 128.0f);
        const float var = qq * (1.0f / 128.0f) - mu * mu;
        st_mu[t] = mu;
        st_rs[t] = rsqrtf(var + 1e-6f);
    }
    __syncthreads();

    // ---------- phase 3: normalize + mask fill in regs ----------
    {
        const long aoff = (long)b * HWW + pos0 + pq * 4;
        uchar4 a4;
        if (mint) {
            const int4 m = *(const int4*)((const int*)act + aoff);
            a4.x = (unsigned char)(m.x != 0); a4.y = (unsigned char)(m.y != 0);
            a4.z = (unsigned char)(m.z != 0); a4.w = (unsigned char)(m.w != 0);
        } else {
            a4 = *(const uchar4*)((const unsigned char*)act + aoff);
        }
        const float4 muv = *(const float4*)&st_mu[pq * 4];
        const float4 rsv = *(const float4*)&st_rs[pq * 4];
        #pragma unroll
        for (int i = 0; i < 8; ++i) {
            const int c = cg * 8 + i;
            const float gg = ldf(gam,  c, bf);
            const float bb = ldf(bet,  c, bf);
            const float mt = ldf(mtok, c, bf);
            float4 w = v[i];
            w.x = a4.x ? fmaf((w.x - muv.x) * rsv.x, gg, bb) : mt;
            w.y = a4.y ? fmaf((w.y - muv.y) * rsv.y, gg, bb) : mt;
            w.z = a4.z ? fmaf((w.z - muv.z) * rsv.z, gg, bb) : mt;
            w.w = a4.w ? fmaf((w.w - muv.w) * rsv.w, gg, bb) : mt;
            v[i] = w;
        }
    }

    // ---------- phase 3.5: write A-fragments (bf16, swizzled slot^p_tile) ----------
    // A-frag (p_tile, kk): lane L, elem j = Xn[c = kk*32 + (L>>4)*8 + j][p = p_tile*16 + (L&15)]
    {
        const int kk = cg >> 2;
        const int sb = 16 * (cg & 3);
        #pragma unroll
        for (int k = 0; k < 4; ++k) {
            const int p    = pq * 4 + k;
            const int pt   = p >> 4;
            const int slot = (p & 15) + sb;
            const int idx  = (pt * 4 + kk) * 64 + (slot ^ pt);
            uint4 wq;
            if      (k == 0) wq = make_uint4(pk2(v[0].x,v[1].x), pk2(v[2].x,v[3].x),
                                             pk2(v[4].x,v[5].x), pk2(v[6].x,v[7].x));
            else if (k == 1) wq = make_uint4(pk2(v[0].y,v[1].y), pk2(v[2].y,v[3].y),
                                             pk2(v[4].y,v[5].y), pk2(v[6].y,v[7].y));
            else if (k == 2) wq = make_uint4(pk2(v[0].z,v[1].z), pk2(v[2].z,v[3].z),
                                             pk2(v[4].z,v[5].z), pk2(v[6].z,v[7].z));
            else             wq = make_uint4(pk2(v[0].w,v[1].w), pk2(v[2].w,v[3].w),
                                             pk2(v[4].w,v[5].w), pk2(v[6].w,v[7].w));
            afrag[idx] = wq;
        }
    }
    __syncthreads();

    // ---------- phase 4: MFMA GEMM  D[p,d] = Xn^T · W^T ----------
    const int wv = __builtin_amdgcn_readfirstlane(t >> 6);   // wave's d-tile

    short8 bw[4];
    #pragma unroll
    for (int kk = 0; kk < 4; ++kk)
        bw[kk] = *(const short8*)(wpack + ((wv * 4 + kk) * 64 + lane) * 8);

    f32x4 acc[8];
    #pragma unroll
    for (int pt = 0; pt < 8; ++pt) acc[pt] = (f32x4){0.f, 0.f, 0.f, 0.f};

    #pragma unroll
    for (int pt = 0; pt < 8; ++pt) {
        #pragma unroll
        for (int kk = 0; kk < 4; ++kk) {
            const short8 a = *(const short8*)&afrag[(pt * 4 + kk) * 64 + (lane ^ pt)];
            acc[pt] = __builtin_amdgcn_mfma_f32_16x16x32_bf16(a, bw[kk], acc[pt], 0, 0, 0);
        }
    }

    // epilogue: bias + stores. D layout: col(d)=lane&15, row(p)=(lane>>4)*4+reg
    const int   dch   = wv * 16 + (lane & 15);
    const float bb    = ldf(bias, dch, bf);
    const long  obase = (long)b * DD * HWW + (long)dch * HWW + pos0 + (lane >> 4) * 4;
    #pragma unroll
    for (int pt = 0; pt < 8; ++pt) {
        float4 o;
        o.x = acc[pt][0] + bb; o.y = acc[pt][1] + bb;
        o.z = acc[pt][2] + bb; o.w = acc[pt][3] + bb;
        *(float4*)(out + obase + pt * 16) = o;
    }
}

extern "C" void kernel_launch(void* const* d_in, const int* in_sizes, int n_in,
                              void* d_out, int out_size, void* d_ws, size_t ws_size,
                              hipStream_t stream) {
    const void* x     = d_in[0];
    const void* act   = d_in[1];
    const void* gamma = d_in[2];
    const void* beta  = d_in[3];
    const void* mtok  = d_in[4];
    const void* convw = d_in[5];
    const void* bias  = d_in[6];
    float* out = (float*)d_out;
    unsigned short* wpack = (unsigned short*)d_ws;   // 32KB B-frag weights

    prep_pack_w<<<64, 256, 0, stream>>>(convw, wpack, gamma);

    const int nblocks = (32 * HWW) / PP;   // 4096
    spark_densify_mfma<<<nblocks, NTHREADS, 0, stream>>>(
        x, act, gamma, beta, mtok, wpack, bias, out);
}